// Round 6
// baseline (379.852 us; speedup 1.0000x reference)
//
#include <hip/hip_runtime.h>
#include <hip/hip_cooperative_groups.h>

namespace cg = cooperative_groups;

#define N_NODES 50000
#define N_EDGES 1600000
#define HEADS 8
#define HIDDEN 64
#define FAN_IN (2*HIDDEN + 1)
#define EPSF 1e-16f

#define NBLK 256               // grid blocks (= CUs, co-resident)
#define NT 512                 // threads per block
#define EPB (N_EDGES / NBLK)   // 6250 edges per block (exact)
#define EPAD 6272
#define BBITS 8
#define BSIZE 256              // nodes per bucket
#define NB 196                 // ceil(50000/256) buckets
#define CAP 12032              // LDS payload capacity (mean 8192, std ~90)

// ---------------- workspace layout (bytes) ----------------
#define COLCNT_OFF  0                                   // int[NBLK*NB]
#define COLBASE_OFF (COLCNT_OFF + 4 * NBLK * NB)        // int[NBLK*NB]
#define TOT_OFF     (COLBASE_OFF + 4 * NBLK * NB)       // int[NB]
#define PAY_OFF     1048576                             // float2[E] = 12.8 MB
#define DLOC_OFF    (PAY_OFF + (size_t)N_EDGES * 8)     // uchar[E] = 1.6 MB
#define WS_NEEDED   (DLOC_OFF + (size_t)N_EDGES)

struct SMem {
    union {
        struct {                       // phases A & C: staged edges
            int   src[EPAD];
            int   dst[EPAD];
            float cm[EPAD];
            unsigned short rank[EPAD]; // local rank within (block,bucket)
        } a;
        struct {                       // phase D: node-sorted payload
            float2 pbuf[CAP];
            int    noff[BSIZE + 1];
        } d;
    } u;
    float cstl[40];        // A1|A2|CC|DD|PP
    int   bstart[NB + 1];  // global bucket starts
    int   hist[BSIZE];     // phase A hist / phase D counts+cursors
    int   sB[NBLK];        // scan scratch
    int   cur[NB];         // phase C scatter cursors
    float FD[BSIZE];       // phase D: nf[dst] for bucket
};

__global__ __launch_bounds__(NT) void mega(
    const float* __restrict__ nf, const float* __restrict__ cmask,
    const float* __restrict__ Wp, const float* __restrict__ bp,
    const float* __restrict__ Wa, const float* __restrict__ ba,
    const float* __restrict__ cp, const float* __restrict__ sc,
    const int* __restrict__ ei,
    int* __restrict__ colcnt, int* __restrict__ colbase, int* __restrict__ tot,
    float2* __restrict__ pay, unsigned char* __restrict__ dloc,
    float* __restrict__ out)
{
    __shared__ SMem s;
    cg::grid_group grid = cg::this_grid();
    const int t = threadIdx.x, blk = blockIdx.x;

    // ---- per-block constant fold: raw = fs*A1 + fd*A2 + c*CC + DD ----
    {
        const int k = t >> 6, j = t & 63;        // 8 waves, one head each
        const float* row = Wa + k * FAN_IN;
        const float w = Wp[j], b = bp[j];
        const float r1 = row[j], r2 = row[HIDDEN + j];
        float a1 = w * r1, a2 = w * r2, d = b * (r1 + r2);
        #pragma unroll
        for (int sft = 32; sft > 0; sft >>= 1) {
            a1 += __shfl_xor(a1, sft);
            a2 += __shfl_xor(a2, sft);
            d  += __shfl_xor(d, sft);
        }
        if (j == 0) {
            s.cstl[k]      = a1;
            s.cstl[8 + k]  = a2;
            s.cstl[16 + k] = row[2 * HIDDEN];
            s.cstl[24 + k] = d + ba[k];
            s.cstl[32 + k] = cp[k];
        }
    }

    // ---- phase A: stage edges once, histogram + local rank ----
    if (t < BSIZE) s.hist[t] = 0;
    __syncthreads();
    const int e0 = blk * EPB;
    for (int i = t; i < EPB; i += NT) {
        const int   sv = ei[e0 + i];
        const int   dv = ei[N_EDGES + e0 + i];
        const float cv = cmask[e0 + i];
        s.u.a.src[i] = sv;
        s.u.a.dst[i] = dv;
        s.u.a.cm[i]  = cv;
        const int bkt = ((unsigned)dv) >> BBITS;
        s.u.a.rank[i] = (unsigned short)atomicAdd(&s.hist[bkt], 1);
    }
    __syncthreads();
    if (t < NB) colcnt[blk * NB + t] = s.hist[t];
    __threadfence();
    grid.sync();

    // ---- phase B: blocks 0..NB-1 scan one column (all scatter blocks of one bucket) ----
    if (blk < NB) {
        if (t < NBLK) s.sB[t] = colcnt[t * NB + blk];
        __syncthreads();
        for (int d = 1; d < NBLK; d <<= 1) {
            const int v = (t < NBLK && t >= d) ? s.sB[t - d] : 0;
            __syncthreads();
            if (t < NBLK && t >= d) s.sB[t] += v;
            __syncthreads();
        }
        if (t < NBLK) colbase[t * NB + blk] = s.sB[t] - colcnt[t * NB + blk];
        if (t == NBLK - 1) tot[blk] = s.sB[NBLK - 1];
    }
    __threadfence();
    grid.sync();

    // ---- phase C: local scan of bucket totals -> bstart; scatter payload ----
    {
        int myTot = 0;
        if (t < NB) myTot = tot[t];
        if (t < NBLK) s.sB[t] = myTot;
        __syncthreads();
        for (int d = 1; d < NBLK; d <<= 1) {
            const int v = (t < NBLK && t >= d) ? s.sB[t - d] : 0;
            __syncthreads();
            if (t < NBLK && t >= d) s.sB[t] += v;
            __syncthreads();
        }
        if (t < NB) {
            const int excl = s.sB[t] - myTot;
            s.bstart[t] = excl;
            s.cur[t]    = excl + colbase[blk * NB + t];
        }
        if (t == 0) s.bstart[NB] = N_EDGES;
        __syncthreads();
        for (int i = t; i < EPB; i += NT) {
            const int dv  = s.u.a.dst[i];
            const int bkt = ((unsigned)dv) >> BBITS;
            const int pos = s.cur[bkt] + s.u.a.rank[i];
            pay[pos]  = make_float2(nf[s.u.a.src[i]], s.u.a.cm[i]);
            dloc[pos] = (unsigned char)(dv & (BSIZE - 1));
        }
    }
    __threadfence();
    grid.sync();

    // ---- phase D: per-bucket counting sort into LDS + atomic-free reduce ----
    if (blk < NB) {
        const int i0 = s.bstart[blk], i1 = s.bstart[blk + 1];
        if (t < BSIZE) {
            s.hist[t] = 0;
            const int n = blk * BSIZE + t;
            s.FD[t] = (n < N_NODES) ? nf[n] : 0.f;
        }
        __syncthreads();
        for (int i = i0 + t; i < i1; i += NT)
            atomicAdd(&s.hist[dloc[i]], 1);
        __syncthreads();
        if (t < BSIZE) s.u.d.noff[t + 1] = s.hist[t];
        if (t == 0) s.u.d.noff[0] = 0;
        __syncthreads();
        for (int d = 1; d < BSIZE; d <<= 1) {
            int v = 0;
            if (t < BSIZE && t >= d) v = s.u.d.noff[t + 1 - d];
            __syncthreads();
            if (t < BSIZE && t >= d) s.u.d.noff[t + 1] += v;
            __syncthreads();
        }
        if (t < BSIZE) s.hist[t] = s.u.d.noff[t];   // cursors = exclusive starts
        __syncthreads();
        for (int i = i0 + t; i < i1; i += NT) {
            const int dl = dloc[i];
            const int p  = atomicAdd(&s.hist[dl], 1);
            if (p < CAP) s.u.d.pbuf[p] = pay[i];
        }
        __syncthreads();

        float A1[8], A2[8], CC[8], DD[8], PP[8];
        #pragma unroll
        for (int k = 0; k < 8; ++k) {
            A1[k] = s.cstl[k];      A2[k] = s.cstl[8 + k];  CC[k] = s.cstl[16 + k];
            DD[k] = s.cstl[24 + k]; PP[k] = s.cstl[32 + k];
        }
        const int j = t >> 1, par = t & 1;
        const int n = blk * BSIZE + j;
        if (n < N_NODES) {
            const int lo = min(s.u.d.noff[j], CAP), hi = min(s.u.d.noff[j + 1], CAP);
            const float fd = s.FD[j];
            float as[8], at[8];
            #pragma unroll
            for (int k = 0; k < 8; ++k) { as[k] = 0.f; at[k] = 0.f; }
            for (int i = lo + par; i < hi; i += 2) {
                const float2 p = s.u.d.pbuf[i];
                #pragma unroll
                for (int k = 0; k < 8; ++k) {
                    float r = p.x * A1[k] + fd * A2[k] + p.y * CC[k] + DD[k];
                    r = (r >= 0.f) ? r : 0.2f * r;
                    r += p.y * PP[k];
                    const float ev = __expf(r);
                    as[k] += ev;
                    at[k] += p.x * ev;
                }
            }
            #pragma unroll
            for (int k = 0; k < 8; ++k) {
                as[k] += __shfl_xor(as[k], 1);
                at[k] += __shfl_xor(at[k], 1);
            }
            if (par == 0) {
                float acc = 0.f;
                #pragma unroll
                for (int k = 0; k < 8; ++k) acc += at[k] / (as[k] + EPSF);
                out[n] = acc * 0.125f * sc[0];
            }
        }
    }
}

// ================= fallback: verified round-5 pipeline =================
#define FNB 196
#define FNH 256
#define FNT 512
#define FEPB 6250
#define FSTRIP 49
#define FCNT_OFF   4096
#define FBASE_OFF  262144

__global__ __launch_bounds__(FNT) void f_prep(
    const float* __restrict__ Wp, const float* __restrict__ bp,
    const float* __restrict__ Wa, const float* __restrict__ ba,
    const float* __restrict__ cp, float* __restrict__ cst) {
    const int k = threadIdx.x >> 6, j = threadIdx.x & 63;
    const float* row = Wa + k * FAN_IN;
    const float w = Wp[j], b = bp[j];
    const float r1 = row[j], r2 = row[HIDDEN + j];
    float a1 = w * r1, a2 = w * r2, d = b * (r1 + r2);
    #pragma unroll
    for (int sft = 32; sft > 0; sft >>= 1) {
        a1 += __shfl_xor(a1, sft); a2 += __shfl_xor(a2, sft); d += __shfl_xor(d, sft);
    }
    if (j == 0) {
        cst[k] = a1; cst[8 + k] = a2; cst[16 + k] = row[2 * HIDDEN];
        cst[24 + k] = d + ba[k]; cst[32 + k] = cp[k];
    }
}

__global__ __launch_bounds__(FNT) void f_hist(const int* __restrict__ ei, int* __restrict__ cnt) {
    __shared__ int hist[FNB];
    const int t = threadIdx.x, blk = blockIdx.x;
    if (t < FNB) hist[t] = 0;
    __syncthreads();
    const int a0 = blk * FEPB, a1 = min(a0 + FEPB, N_EDGES);
    for (int e = a0 + t; e < a1; e += FNT)
        atomicAdd(&hist[((unsigned)ei[N_EDGES + e]) >> BBITS], 1);
    __syncthreads();
    if (t < FNB) cnt[t * FNH + blk] = hist[t];
}

__global__ __launch_bounds__(1024) void f_scan(const int* __restrict__ cnt, int* __restrict__ base) {
    __shared__ int lds[1024];
    const int t = threadIdx.x;
    int sm = 0;
    #pragma unroll
    for (int jj = 0; jj < FSTRIP; ++jj) sm += cnt[t * FSTRIP + jj];
    lds[t] = sm;
    __syncthreads();
    for (int d = 1; d < 1024; d <<= 1) {
        const int v = (t >= d) ? lds[t - d] : 0;
        __syncthreads();
        lds[t] += v;
        __syncthreads();
    }
    int run = lds[t] - sm;
    #pragma unroll
    for (int jj = 0; jj < FSTRIP; ++jj) {
        const int i = t * FSTRIP + jj;
        const int v = cnt[i];
        base[i] = run;
        run += v;
    }
}

__global__ __launch_bounds__(FNT) void f_scatter(const int* __restrict__ ei,
                                                 const float* __restrict__ cmask,
                                                 const float* __restrict__ nf,
                                                 const int* __restrict__ base,
                                                 float2* __restrict__ pay,
                                                 unsigned char* __restrict__ dl) {
    __shared__ int cur[FNB];
    const int t = threadIdx.x, blk = blockIdx.x;
    if (t < FNB) cur[t] = base[t * FNH + blk];
    __syncthreads();
    const int a0 = blk * FEPB, a1 = min(a0 + FEPB, N_EDGES);
    for (int e = a0 + t; e < a1; e += FNT) {
        const int src = ei[e], dst = ei[N_EDGES + e];
        const int bkt = ((unsigned)dst) >> BBITS;
        const int pos = atomicAdd(&cur[bkt], 1);
        pay[pos] = make_float2(nf[src], cmask[e]);
        dl[pos] = (unsigned char)(dst & (BSIZE - 1));
    }
}

__global__ __launch_bounds__(FNT) void f_fused(const float* __restrict__ nf,
                                               const float* __restrict__ cst_g,
                                               const int* __restrict__ base,
                                               const float2* __restrict__ pay,
                                               const unsigned char* __restrict__ dl,
                                               const float* __restrict__ scaler,
                                               float* __restrict__ out) {
    __shared__ float2 pbuf[CAP];
    __shared__ int    hist[BSIZE];
    __shared__ int    noff[BSIZE + 1];
    __shared__ float  FDl[BSIZE];
    __shared__ float  cstl[40];
    const int t = threadIdx.x, b = blockIdx.x;
    if (t < 40) cstl[t] = cst_g[t];
    if (t < BSIZE) {
        hist[t] = 0;
        const int n = b * BSIZE + t;
        FDl[t] = (n < N_NODES) ? nf[n] : 0.f;
    }
    if (t == FNT - 1) noff[0] = 0;
    __syncthreads();
    const int i0 = base[b * FNH];
    const int i1 = (b == FNB - 1) ? N_EDGES : base[(b + 1) * FNH];
    for (int i = i0 + t; i < i1; i += FNT) atomicAdd(&hist[dl[i]], 1);
    __syncthreads();
    if (t < BSIZE) noff[t + 1] = hist[t];
    __syncthreads();
    for (int d = 1; d < BSIZE; d <<= 1) {
        int v = 0;
        if (t < BSIZE && t >= d) v = noff[t + 1 - d];
        __syncthreads();
        if (t < BSIZE && t >= d) noff[t + 1] += v;
        __syncthreads();
    }
    if (t < BSIZE) hist[t] = noff[t];
    __syncthreads();
    for (int i = i0 + t; i < i1; i += FNT) {
        const int d2 = dl[i];
        const int p = atomicAdd(&hist[d2], 1);
        if (p < CAP) pbuf[p] = pay[i];
    }
    __syncthreads();
    float A1[8], A2[8], CC[8], DD[8], PP[8];
    #pragma unroll
    for (int k = 0; k < 8; ++k) {
        A1[k] = cstl[k]; A2[k] = cstl[8 + k]; CC[k] = cstl[16 + k];
        DD[k] = cstl[24 + k]; PP[k] = cstl[32 + k];
    }
    const int j = t >> 1, par = t & 1;
    const int n = b * BSIZE + j;
    if (n < N_NODES) {
        const int lo = min(noff[j], CAP), hi = min(noff[j + 1], CAP);
        const float fd = FDl[j];
        float as[8], at[8];
        #pragma unroll
        for (int k = 0; k < 8; ++k) { as[k] = 0.f; at[k] = 0.f; }
        for (int i = lo + par; i < hi; i += 2) {
            const float2 p = pbuf[i];
            #pragma unroll
            for (int k = 0; k < 8; ++k) {
                float r = p.x * A1[k] + fd * A2[k] + p.y * CC[k] + DD[k];
                r = (r >= 0.f) ? r : 0.2f * r;
                r += p.y * PP[k];
                const float ev = __expf(r);
                as[k] += ev;
                at[k] += p.x * ev;
            }
        }
        #pragma unroll
        for (int k = 0; k < 8; ++k) {
            as[k] += __shfl_xor(as[k], 1);
            at[k] += __shfl_xor(at[k], 1);
        }
        if (par == 0) {
            float acc = 0.f;
            #pragma unroll
            for (int k = 0; k < 8; ++k) acc += at[k] / (as[k] + EPSF);
            out[n] = acc * 0.125f * scaler[0];
        }
    }
}

extern "C" void kernel_launch(void* const* d_in, const int* in_sizes, int n_in,
                              void* d_out, int out_size, void* d_ws, size_t ws_size,
                              hipStream_t stream) {
    const float* nf    = (const float*)d_in[0];
    const float* cmask = (const float*)d_in[1];
    const float* Wp    = (const float*)d_in[2];
    const float* bp    = (const float*)d_in[3];
    const float* Wa    = (const float*)d_in[4];
    const float* ba    = (const float*)d_in[5];
    const float* cp    = (const float*)d_in[6];
    const float* sc    = (const float*)d_in[7];
    const int*   ei    = (const int*)d_in[8];

    char* ws = (char*)d_ws;
    int*           colcnt  = (int*)(ws + COLCNT_OFF);
    int*           colbase = (int*)(ws + COLBASE_OFF);
    int*           tot     = (int*)(ws + TOT_OFF);
    float2*        pay     = (float2*)(ws + PAY_OFF);
    unsigned char* dl      = (unsigned char*)(ws + DLOC_OFF);
    float*         outp    = (float*)d_out;

    void* args[] = {(void*)&nf, (void*)&cmask, (void*)&Wp, (void*)&bp,
                    (void*)&Wa, (void*)&ba, (void*)&cp, (void*)&sc,
                    (void*)&ei, (void*)&colcnt, (void*)&colbase, (void*)&tot,
                    (void*)&pay, (void*)&dl, (void*)&outp};

    hipError_t err = hipLaunchCooperativeKernel((const void*)mega, dim3(NBLK), dim3(NT),
                                                args, 0, stream);
    if (err != hipSuccess) {
        // fallback: verified 5-kernel round-5 pipeline
        float* cst  = (float*)(ws + 0);
        int*   cnt  = (int*)(ws + FCNT_OFF);
        int*   base = (int*)(ws + FBASE_OFF);
        f_prep<<<1, FNT, 0, stream>>>(Wp, bp, Wa, ba, cp, cst);
        f_hist<<<FNH, FNT, 0, stream>>>(ei, cnt);
        f_scan<<<1, 1024, 0, stream>>>(cnt, base);
        f_scatter<<<FNH, FNT, 0, stream>>>(ei, cmask, nf, base, pay, dl);
        f_fused<<<FNB, FNT, 0, stream>>>(nf, cst, base, pay, dl, sc, outp);
    }
}

// Round 7
// 131.712 us; speedup vs baseline: 2.8840x; 2.8840x over previous
//
#include <hip/hip_runtime.h>

#define N_NODES 50000
#define N_EDGES 1600000
#define HEADS 8
#define HIDDEN 64
#define FAN_IN (2*HIDDEN + 1)
#define EPSF 1e-16f

#define BBITS 8
#define BSIZE 256               // nodes per bucket
#define NB 196                  // buckets
#define NSB 512                 // scatter/hist blocks
#define EPB 3125                // edges per scatter block (512*3125 = 1.6M exact)
#define NTS 256                 // threads in hist/scatter
#define NTR 512                 // threads in reduce
#define CAP 12032               // reduce LDS payload capacity (mean 8192, sigma 90)

// ---------------- workspace layout (bytes) ----------------
#define CNT_OFF   0                                  // int[NB*NSB] cnt[bkt*NSB+blk]
#define COLB_OFF  524288                             // int[NB*NSB] colbase[bkt*NSB+blk]
#define TOT_OFF   1048576                            // int[NB]
#define PAY_OFF   2097152                            // float2[E] = 12.8 MB
#define DL_OFF    (PAY_OFF + (size_t)N_EDGES * 8)    // uchar[E]
#define WS_NEEDED (DL_OFF + (size_t)N_EDGES)

// K1: per-block LDS histogram of dst bucket -> cnt[bkt*NSB+blk]
__global__ __launch_bounds__(NTS) void k_hist(const int* __restrict__ ei,
                                              int* __restrict__ cnt) {
    __shared__ int hist[NB];
    const int t = threadIdx.x, blk = blockIdx.x;
    if (t < NB) hist[t] = 0;
    __syncthreads();
    const int e0 = blk * EPB;
    for (int i = t; i < EPB; i += NTS)
        atomicAdd(&hist[((unsigned)ei[N_EDGES + e0 + i]) >> BBITS], 1);
    __syncthreads();
    if (t < NB) cnt[t * NSB + blk] = hist[t];
}

// K2: 196 blocks; block b scans its contiguous 512-entry column ->
// colbase (exclusive within bucket) and tot[b]
__global__ __launch_bounds__(NSB) void k_colscan(const int* __restrict__ cnt,
                                                 int* __restrict__ colbase,
                                                 int* __restrict__ tot) {
    __shared__ int lds[NSB];
    const int t = threadIdx.x, b = blockIdx.x;
    const int v = cnt[b * NSB + t];
    lds[t] = v;
    __syncthreads();
    for (int d = 1; d < NSB; d <<= 1) {
        const int x = (t >= d) ? lds[t - d] : 0;
        __syncthreads();
        lds[t] += x;
        __syncthreads();
    }
    colbase[b * NSB + t] = lds[t] - v;
    if (t == NSB - 1) tot[b] = lds[t];
}

// K3: presort in LDS, emit bucket-sorted payload with coalesced run writes.
__global__ __launch_bounds__(NTS) void k_scatter(const int* __restrict__ ei,
                                                 const float* __restrict__ cmask,
                                                 const float* __restrict__ nf,
                                                 const int* __restrict__ colbase,
                                                 const int* __restrict__ tot,
                                                 float2* __restrict__ pay,
                                                 unsigned char* __restrict__ dl8) {
    __shared__ int pr[EPB];          // packed bkt<<20 | dl<<12 | rank
    __shared__ int inv[EPB];         // inverse permutation
    __shared__ int hist[NB];
    __shared__ int lstart[NB];
    __shared__ int cur[NB];          // global write base minus lstart
    __shared__ int scr[256];
    const int t = threadIdx.x, blk = blockIdx.x;
    const int e0 = blk * EPB;

    if (t < NB) hist[t] = 0;
    __syncthreads();

    // stage: bucket + local rank per edge
    for (int i = t; i < EPB; i += NTS) {
        const int dv = ei[N_EDGES + e0 + i];
        const int bkt = ((unsigned)dv) >> BBITS;
        const int rank = atomicAdd(&hist[bkt], 1);
        pr[i] = (bkt << 20) | ((dv & (BSIZE - 1)) << 12) | rank;
    }
    __syncthreads();

    // scan 1: bucket totals (global) -> bstart; scan 2: local hist -> lstart
    int mytot = (t < NB) ? tot[t] : 0;
    scr[t] = mytot;
    __syncthreads();
    for (int d = 1; d < 256; d <<= 1) {
        const int x = (t >= d) ? scr[t - d] : 0;
        __syncthreads();
        scr[t] += x;
        __syncthreads();
    }
    const int bstart_t = scr[t] - mytot;           // exclusive global bucket start
    __syncthreads();
    int myh = (t < NB) ? hist[t] : 0;
    scr[t] = myh;
    __syncthreads();
    for (int d = 1; d < 256; d <<= 1) {
        const int x = (t >= d) ? scr[t - d] : 0;
        __syncthreads();
        scr[t] += x;
        __syncthreads();
    }
    if (t < NB) {
        const int ls = scr[t] - myh;               // local exclusive start
        lstart[t] = ls;
        cur[t] = bstart_t + colbase[t * NSB + blk] - ls;
    }
    __syncthreads();

    // inverse permutation: sorted slot p -> edge i
    for (int i = t; i < EPB; i += NTS) {
        const int u = pr[i];
        inv[lstart[u >> 20] + (u & 0xFFF)] = i;
    }
    __syncthreads();

    // emit in sorted order: consecutive p -> consecutive global pos within a run
    for (int p = t; p < EPB; p += NTS) {
        const int i = inv[p];
        const int u = pr[i];
        const int bkt = u >> 20;
        const int g = cur[bkt] + p;
        const int e = e0 + i;
        pay[g] = make_float2(nf[ei[e]], cmask[e]);
        dl8[g] = (unsigned char)((u >> 12) & 255);
    }
}

// K4: per-bucket counting sort into LDS + atomic-free register reduce (+inline cst)
__global__ __launch_bounds__(NTR) void k_reduce(const float* __restrict__ nf,
                                                const float* __restrict__ Wp,
                                                const float* __restrict__ bp,
                                                const float* __restrict__ Wa,
                                                const float* __restrict__ ba,
                                                const float* __restrict__ cp,
                                                const float* __restrict__ sc,
                                                const int* __restrict__ tot,
                                                const float2* __restrict__ pay,
                                                const unsigned char* __restrict__ dl8,
                                                float* __restrict__ out) {
    __shared__ float2 pbuf[CAP];          // 96256 B
    __shared__ int    hist[BSIZE];
    __shared__ int    noff[BSIZE + 1];
    __shared__ float  FD[BSIZE];
    __shared__ float  cstl[40];
    __shared__ int    scr[256];
    __shared__ int    sI0;
    const int t = threadIdx.x, b = blockIdx.x;

    // inline constant fold (8 waves, one head each)
    {
        const int k = t >> 6, j = t & 63;
        const float* row = Wa + k * FAN_IN;
        const float w = Wp[j], bb = bp[j];
        const float r1 = row[j], r2 = row[HIDDEN + j];
        float a1 = w * r1, a2 = w * r2, d = bb * (r1 + r2);
        #pragma unroll
        for (int s = 32; s > 0; s >>= 1) {
            a1 += __shfl_xor(a1, s);
            a2 += __shfl_xor(a2, s);
            d  += __shfl_xor(d, s);
        }
        if (j == 0) {
            cstl[k]      = a1;
            cstl[8 + k]  = a2;
            cstl[16 + k] = row[2 * HIDDEN];
            cstl[24 + k] = d + ba[k];
            cstl[32 + k] = cp[k];
        }
    }

    // bucket start from tot scan
    {
        int v = 0;
        if (t < 256) v = (t < NB) ? tot[t] : 0;
        if (t < 256) scr[t] = v;
        __syncthreads();
        for (int d = 1; d < 256; d <<= 1) {
            int x = 0;
            if (t < 256 && t >= d) x = scr[t - d];
            __syncthreads();
            if (t < 256 && t >= d) scr[t] += x;
            __syncthreads();
        }
        if (t == b) sI0 = scr[t] - v;   // exclusive prefix at own bucket
        __syncthreads();
    }
    const int i0 = sI0;
    const int i1 = i0 + tot[b];

    if (t < BSIZE) {
        hist[t] = 0;
        const int n = b * BSIZE + t;
        FD[t] = (n < N_NODES) ? nf[n] : 0.f;
    }
    if (t == 0) noff[0] = 0;
    __syncthreads();

    // pass 1: node histogram
    for (int i = i0 + t; i < i1; i += NTR)
        atomicAdd(&hist[dl8[i]], 1);
    __syncthreads();
    if (t < BSIZE) noff[t + 1] = hist[t];
    __syncthreads();
    for (int d = 1; d < BSIZE; d <<= 1) {
        int v = 0;
        if (t < BSIZE && t >= d) v = noff[t + 1 - d];
        __syncthreads();
        if (t < BSIZE && t >= d) noff[t + 1] += v;
        __syncthreads();
    }
    if (t < BSIZE) hist[t] = noff[t];   // cursors
    __syncthreads();

    // pass 2: node-sorted scatter into LDS
    for (int i = i0 + t; i < i1; i += NTR) {
        const int dl = dl8[i];
        const int p = atomicAdd(&hist[dl], 1);
        if (p < CAP) pbuf[p] = pay[i];
    }
    __syncthreads();

    // register reduce: 2 threads per node
    float A1[8], A2[8], CC[8], DD[8], PP[8];
    #pragma unroll
    for (int k = 0; k < 8; ++k) {
        A1[k] = cstl[k];      A2[k] = cstl[8 + k];  CC[k] = cstl[16 + k];
        DD[k] = cstl[24 + k]; PP[k] = cstl[32 + k];
    }
    const int j = t >> 1, par = t & 1;
    const int n = b * BSIZE + j;
    if (n < N_NODES) {
        const int lo = min(noff[j], CAP), hi = min(noff[j + 1], CAP);
        const float fd = FD[j];
        float as[8], at[8];
        #pragma unroll
        for (int k = 0; k < 8; ++k) { as[k] = 0.f; at[k] = 0.f; }
        for (int i = lo + par; i < hi; i += 2) {
            const float2 p = pbuf[i];
            #pragma unroll
            for (int k = 0; k < 8; ++k) {
                float r = p.x * A1[k] + fd * A2[k] + p.y * CC[k] + DD[k];
                r = (r >= 0.f) ? r : 0.2f * r;
                r += p.y * PP[k];
                const float ev = __expf(r);
                as[k] += ev;
                at[k] += p.x * ev;
            }
        }
        #pragma unroll
        for (int k = 0; k < 8; ++k) {
            as[k] += __shfl_xor(as[k], 1);
            at[k] += __shfl_xor(at[k], 1);
        }
        if (par == 0) {
            float acc = 0.f;
            #pragma unroll
            for (int k = 0; k < 8; ++k) acc += at[k] / (as[k] + EPSF);
            out[n] = acc * 0.125f * sc[0];
        }
    }
}

// ---------------- fallback (round-2 atomic version) for small ws ----------------
__global__ __launch_bounds__(256) void cagat_edge_atomic(
    const float* __restrict__ nf, const float* __restrict__ cmask,
    const float* __restrict__ Wp, const float* __restrict__ bp,
    const float* __restrict__ Wa, const float* __restrict__ ba,
    const float* __restrict__ cp, const int* __restrict__ ei,
    float* __restrict__ S, float* __restrict__ T) {
    __shared__ float A1[HEADS], A2[HEADS], CC[HEADS], DD[HEADS], PP[HEADS];
    const int t = threadIdx.x;
    if (t < HEADS) {
        const float* row = Wa + t * FAN_IN;
        float a1 = 0.f, a2 = 0.f, d = 0.f;
        for (int h = 0; h < HIDDEN; ++h) {
            float w = Wp[h], b = bp[h];
            a1 += w * row[h]; a2 += w * row[HIDDEN + h];
            d += b * (row[h] + row[HIDDEN + h]);
        }
        A1[t] = a1; A2[t] = a2; CC[t] = row[2*HIDDEN]; DD[t] = d + ba[t]; PP[t] = cp[t];
    }
    __syncthreads();
    const int e = blockIdx.x * 256 + t;
    if (e >= N_EDGES) return;
    const int src = ei[e], dst = ei[N_EDGES + e];
    const float fs = nf[src], fd = nf[dst], c = cmask[e];
    #pragma unroll
    for (int k = 0; k < HEADS; ++k) {
        float r = fs * A1[k] + fd * A2[k] + c * CC[k] + DD[k];
        r = (r >= 0.f) ? r : 0.2f * r;
        r += c * PP[k];
        float ev = __expf(r);
        atomicAdd(S + dst * HEADS + k, ev);
        atomicAdd(T + dst * HEADS + k, fs * ev);
    }
}

__global__ __launch_bounds__(256) void cagat_node_atomic(
    const float* __restrict__ S, const float* __restrict__ T,
    const float* __restrict__ scaler, float* __restrict__ out) {
    const int n = blockIdx.x * 256 + threadIdx.x;
    if (n >= N_NODES) return;
    float acc = 0.f;
    #pragma unroll
    for (int k = 0; k < HEADS; ++k)
        acc += T[n * HEADS + k] / (S[n * HEADS + k] + EPSF);
    out[n] = acc * 0.125f * scaler[0];
}

extern "C" void kernel_launch(void* const* d_in, const int* in_sizes, int n_in,
                              void* d_out, int out_size, void* d_ws, size_t ws_size,
                              hipStream_t stream) {
    const float* nf    = (const float*)d_in[0];
    const float* cmask = (const float*)d_in[1];
    const float* Wp    = (const float*)d_in[2];
    const float* bp    = (const float*)d_in[3];
    const float* Wa    = (const float*)d_in[4];
    const float* ba    = (const float*)d_in[5];
    const float* cp    = (const float*)d_in[6];
    const float* sc    = (const float*)d_in[7];
    const int*   ei    = (const int*)d_in[8];

    char* ws = (char*)d_ws;

    if (ws_size >= WS_NEEDED) {
        int*           cnt     = (int*)(ws + CNT_OFF);
        int*           colbase = (int*)(ws + COLB_OFF);
        int*           tot     = (int*)(ws + TOT_OFF);
        float2*        pay     = (float2*)(ws + PAY_OFF);
        unsigned char* dl      = (unsigned char*)(ws + DL_OFF);

        k_hist<<<NSB, NTS, 0, stream>>>(ei, cnt);
        k_colscan<<<NB, NSB, 0, stream>>>(cnt, colbase, tot);
        k_scatter<<<NSB, NTS, 0, stream>>>(ei, cmask, nf, colbase, tot, pay, dl);
        k_reduce<<<NB, NTR, 0, stream>>>(nf, Wp, bp, Wa, ba, cp, sc, tot, pay, dl,
                                         (float*)d_out);
    } else {
        float* S = (float*)d_ws;
        float* T = S + (size_t)N_NODES * HEADS;
        hipMemsetAsync(d_ws, 0, (size_t)N_NODES * HEADS * 2 * sizeof(float), stream);
        cagat_edge_atomic<<<(N_EDGES + 255) / 256, 256, 0, stream>>>(
            nf, cmask, Wp, bp, Wa, ba, cp, ei, S, T);
        cagat_node_atomic<<<(N_NODES + 255) / 256, 256, 0, stream>>>(
            S, T, sc, (float*)d_out);
    }
}